// Round 5
// baseline (242.062 us; speedup 1.0000x reference)
//
#include <hip/hip_runtime.h>
#include <math.h>

#define TSTEPS 48
#define FEAT 60
#define BATCH 128
#define BLOCK 512
#define TWO_PI_F 6.2831853071795864769f

// BLOCK=512: 8 waves/block -> 2 waves/SIMD, 4 amps/thread.
// State-bit map: qubits q0=l5 q1=r1 q2=r0 q3=l4 q4=l3 q5=l2 q6=l1 q7=l0
//                q8=w2 q9=w1 q10=w0
// L1 1q gates folded into embedding; L1 CRXs local. L2 q0..q7 local (CRX
// fused). L2 q8..q10 = 8x8 wave merge — OFF the recurrence path (unitarity:
// pre-merge probs are exact for q0..q7), software-pipelined: its o3..o5
// outputs finalize at the NEXT step's barrier A.

struct Cf { float r, i; };
__device__ __forceinline__ Cf cmul(Cf a, Cf b){ return {a.r*b.r - a.i*b.i, a.r*b.i + a.i*b.r}; }
__device__ __forceinline__ Cf cadd(Cf a, Cf b){ return {a.r+b.r, a.i+b.i}; }
__device__ __forceinline__ void mm2(const Cf A[4], const Cf B[4], Cf D[4]) {
  D[0] = cadd(cmul(A[0],B[0]), cmul(A[1],B[2]));
  D[1] = cadd(cmul(A[0],B[1]), cmul(A[1],B[3]));
  D[2] = cadd(cmul(A[2],B[0]), cmul(A[3],B[2]));
  D[3] = cadd(cmul(A[2],B[1]), cmul(A[3],B[3]));
}

struct Mat { float4 r0, r1; };

__device__ __forceinline__ float rlane(float v, int l) {
  return __int_as_float(__builtin_amdgcn_readlane(__float_as_int(v), l));
}

__device__ __forceinline__ float dpp(float v, int ctrl) = delete;
template<int CTRL>
__device__ __forceinline__ float dppf(float v) {
  return __int_as_float(__builtin_amdgcn_mov_dpp(__float_as_int(v), CTRL, 0xF, 0xF, true));
}

// xor-lane exchange. 1:quad_perm 2:quad_perm 4:reverse∘half_mirror 8:row_ror:8
// 16,32: ds_swizzle via __shfl_xor
template<int M>
__device__ __forceinline__ float sx(float v) {
  if constexpr (M == 1)      return dppf<0xB1>(v);
  else if constexpr (M == 2) return dppf<0x4E>(v);
  else if constexpr (M == 4) return dppf<0x141>(dppf<0x1B>(v));  // xor3 then xor7
  else if constexpr (M == 8) return dppf<0x128>(v);              // row_ror:8
  else return __shfl_xor(v, M, 64);
}

__device__ __forceinline__ Cf csel(float4 v, int b) {
  return b ? Cf{v.z, v.w} : Cf{v.x, v.y};
}

__device__ __forceinline__ float4 rowsel(const float* M, int bit) {
  return bit ? make_float4(M[6],M[7],M[4],M[5])
             : make_float4(M[0],M[1],M[2],M[3]);
}

template<int MASK>
__device__ __forceinline__ void lgate(float2& a, float4 m) {
  float px = sx<MASK>(a.x), py = sx<MASK>(a.y);
  float ax = a.x, ay = a.y;
  a.x = m.x*ax - m.y*ay + m.z*px - m.w*py;
  a.y = m.x*ay + m.y*ax + m.z*py + m.w*px;
}

__device__ __forceinline__ void rgate(float2& A, float2& B, Mat M) {
  float2 A0 = A, B0 = B;
  A.x = M.r0.x*A0.x - M.r0.y*A0.y + M.r0.z*B0.x - M.r0.w*B0.y;
  A.y = M.r0.x*A0.y + M.r0.y*A0.x + M.r0.z*B0.y + M.r0.w*B0.x;
  B.x = M.r1.x*A0.x - M.r1.y*A0.y + M.r1.z*B0.x - M.r1.w*B0.y;
  B.y = M.r1.x*A0.y + M.r1.y*A0.x + M.r1.z*B0.y + M.r1.w*B0.x;
}

__device__ __forceinline__ void rxmix(float2& a0, float2& a1, float c, float s) {
  float n0x = c*a0.x + s*a1.y, n0y = c*a0.y - s*a1.x;
  float n1x = c*a1.x + s*a0.y, n1y = c*a1.y - s*a0.x;
  a0.x = n0x; a0.y = n0y; a1.x = n1x; a1.y = n1y;
}

template<int MASK>
__device__ __forceinline__ void rxs(float2& a, float c, float s) {
  float px = sx<MASK>(a.x), py = sx<MASK>(a.y);
  float ax = a.x, ay = a.y;
  a.x = c*ax + s*py;
  a.y = c*ay - s*px;
}

__global__ __launch_bounds__(BLOCK, 2)
void qrnn_kernel(const float* __restrict__ x, const float* __restrict__ hin,
                 const float* __restrict__ params, float* __restrict__ out) {
  const int b    = blockIdx.x;
  const int tid  = threadIdx.x;
  const int lane = tid & 63;
  const int w    = tid >> 6;                   // 0..7
  const int l5 = (lane>>5)&1, l4=(lane>>4)&1, l3=(lane>>3)&1,
            l2 = (lane>>2)&1, l1=(lane>>1)&1, l0=lane&1;

  __shared__ __align__(16) float matU[2][11][8];
  __shared__ __align__(16) float matVs[4][8];
  __shared__ float  xs[TSTEPS*FEAT];
  __shared__ float  pooled[TSTEPS][6];
  __shared__ float4 evis[TSTEPS][6];
  __shared__ __align__(16) float4 xbA[512];     // merge plane (a0,a1), lane-contiguous
  __shared__ __align__(16) float4 xbB[512];     // merge plane (a2,a3)
  __shared__ __align__(32) float wredT[8][8];   // [slot][wave]
  __shared__ __align__(32) float sredT[8];      // per-wave post-merge S

  // ---- stage x ----
  for (int j = tid; j < TSTEPS*FEAT; j += BLOCK)
    xs[j] = x[(size_t)b*TSTEPS*FEAT + j];
  // ---- fused per-(layer,qubit) U = RZ*RY*RX ----
  if (tid < 22) {
    int l = tid / 11, k = tid % 11;
    int base = 37 * l;
    int off = (k < 5) ? (base + 3*k) : (base + 19 + 3*(k-5));
    float px = params[off], py = params[off+1], pz = params[off+2];
    float cx = cosf(0.5f*px), sxn = sinf(0.5f*px);
    float cy = cosf(0.5f*py), syn = sinf(0.5f*py);
    float cz = cosf(0.5f*pz), szn = sinf(0.5f*pz);
    Cf RX[4] = {{cx,0.f},{0.f,-sxn},{0.f,-sxn},{cx,0.f}};
    Cf RY[4] = {{cy,0.f},{-syn,0.f},{syn,0.f},{cy,0.f}};
    Cf RZ[4] = {{cz,-szn},{0.f,0.f},{0.f,0.f},{cz,szn}};
    Cf M[4], U[4];
    mm2(RY, RX, M);
    mm2(RZ, M,  U);
    float* d = &matU[l][k][0];
    d[0]=U[0].r; d[1]=U[0].i; d[2]=U[1].r; d[3]=U[1].i;
    d[4]=U[2].r; d[5]=U[2].i; d[6]=U[3].r; d[7]=U[3].i;
  }
  __syncthreads();
  if (tid < 4) {                                // V[i] = RX(th_L2,i)*U2[i+1]
    float th = params[37 + 15 + tid];
    float c = cosf(0.5f*th), s = sinf(0.5f*th);
    const float* Up = &matU[1][tid+1][0];
    Cf U00{Up[0],Up[1]}, U01{Up[2],Up[3]}, U10{Up[4],Up[5]}, U11{Up[6],Up[7]};
    Cf ms{0.f, -s};
    Cf V00 = cadd(Cf{c*U00.r, c*U00.i}, cmul(ms, U10));
    Cf V01 = cadd(Cf{c*U01.r, c*U01.i}, cmul(ms, U11));
    Cf V10 = cadd(cmul(ms, U00), Cf{c*U10.r, c*U10.i});
    Cf V11 = cadd(cmul(ms, U01), Cf{c*U11.r, c*U11.i});
    float* d = &matVs[tid][0];
    d[0]=V00.r; d[1]=V00.i; d[2]=V01.r; d[3]=V01.i;
    d[4]=V10.r; d[5]=V10.i; d[6]=V11.r; d[7]=V11.i;
  }
  for (int j = tid; j < TSTEPS*6; j += BLOCK) {
    int t = j / 6, k = j % 6;
    const float* xp = &xs[t*FEAT + k*10];
    float s = 0.f;
    #pragma unroll
    for (int f = 0; f < 10; ++f) s += xp[f];
    pooled[t][k] = s * 0.1f;
  }
  __syncthreads();
  for (int j = tid; j < TSTEPS*6; j += BLOCK) {
    int t = j / 6, k = j % 6;
    float mn = pooled[t][0], mx = pooled[t][0];
    #pragma unroll
    for (int v = 1; v < 6; ++v) { mn = fminf(mn, pooled[t][v]); mx = fmaxf(mx, pooled[t][v]); }
    float ang = TWO_PI_F * (pooled[t][k] - mn) / (mx - mn + 1e-8f);
    float c = __cosf(0.5f*ang), s = __sinf(0.5f*ang);
    const float* U = &matU[0][5+k][0];
    evis[t][k] = make_float4(U[0]*c + U[3]*s, U[1]*c - U[2]*s,
                             U[4]*c + U[7]*s, U[5]*c - U[6]*s);
  }

  // ---- per-thread loop-invariant gate data ----
  Mat Mq1;
  { const float* p = l5 ? &matVs[0][0] : &matU[1][1][0];
    Mq1.r0 = *(const float4*)p; Mq1.r1 = *(const float4*)(p+4); }
  Mat Mq2a, Mq2b;
  Mq2a.r0 = *(const float4*)&matU[1][2][0]; Mq2a.r1 = *(const float4*)&matU[1][2][4];
  Mq2b.r0 = *(const float4*)&matVs[1][0];   Mq2b.r1 = *(const float4*)&matVs[1][4];
  float4 q0row  = rowsel(&matU[1][0][0], l5);
  float4 q3rowU = rowsel(&matU[1][3][0], l4);
  float4 q3rowV = rowsel(&matVs[2][0],   l4);
  float4 q4row  = rowsel(l4 ? &matVs[3][0] : &matU[1][4][0], l3);
  float4 q5row  = rowsel(&matU[1][5][0], l2);
  float4 q6row  = rowsel(&matU[1][6][0], l1);
  float4 q7row  = rowsel(&matU[1][7][0], l0);
  float c1p, s1p, c2v, s2v, c3v, s3v, c4p, s4p;
  { float th = params[15]; float c = cosf(0.5f*th), s = sinf(0.5f*th);
    c1p = l5 ? c : 1.f; s1p = l5 ? s : 0.f; }
  { float th = params[16]; c2v = cosf(0.5f*th); s2v = sinf(0.5f*th); }
  { float th = params[17]; c3v = cosf(0.5f*th); s3v = sinf(0.5f*th); }
  { float th = params[18]; float c = cosf(0.5f*th), s = sinf(0.5f*th);
    c4p = l4 ? c : 1.f; s4p = l4 ? s : 0.f; }
  // merge coefficients (8x8 tensor row, XOR-indexed)
  float dR[8], dI[8];
  { const int i2 = (w>>2)&1, i1 = (w>>1)&1, i0 = w&1;
    const float* u8  = &matU[1][8][0];
    const float* u9  = &matU[1][9][0];
    const float* u10 = &matU[1][10][0];
    #pragma unroll
    for (int k = 0; k < 8; ++k) {
      int j = w ^ k;
      int j2 = (j>>2)&1, j1 = (j>>1)&1, j0 = j&1;
      Cf a8 {u8 [(i2*2+j2)*2], u8 [(i2*2+j2)*2+1]};
      Cf a9 {u9 [(i1*2+j1)*2], u9 [(i1*2+j1)*2+1]};
      Cf a10{u10[(i0*2+j0)*2], u10[(i0*2+j0)*2+1]};
      Cf c = cmul(cmul(a8, a9), a10);
      dR[k] = c.r; dI[k] = c.i;
    }
  }
  const int lq = (lane < 5) ? lane : 0;
  float4 mH0 = *(const float4*)&matU[0][lq][0];
  float4 mH1 = *(const float4*)&matU[0][lq][4];
  float hreg = (lane < 5) ? hin[b*5 + lane] : 0.f;
  __syncthreads();

  #pragma unroll 1
  for (int t = 0; t < TSTEPS; ++t) {
    // ---- visible embed factor ----
    float4 v5 = evis[t][0], v6 = evis[t][1], v7 = evis[t][2],
           v8 = evis[t][3], v9 = evis[t][4], v10 = evis[t][5];
    Cf Fv = csel(v8, (w>>2)&1);
    Fv = cmul(Fv, csel(v9, (w>>1)&1));
    Fv = cmul(Fv, csel(v10, w&1));
    Fv = cmul(Fv, csel(v5, l2));
    Fv = cmul(Fv, csel(v6, l1));
    Fv = cmul(Fv, csel(v7, l0));

    // ---- hidden e-vectors ----
    float chh = __cosf(0.5f*hreg), shh = __sinf(0.5f*hreg);
    float e0r_ = mH0.x*chh + mH0.w*shh;
    float e0i_ = mH0.y*chh - mH0.z*shh;
    float e1r_ = mH1.x*chh + mH1.w*shh;
    float e1i_ = mH1.y*chh - mH1.z*shh;
    Cf Eq0, Eq3, Eq4, E1[2], E2[2];
    { float A=rlane(e0r_,0), B=rlane(e0i_,0), C=rlane(e1r_,0), D=rlane(e1i_,0);
      Eq0 = { l5 ? C : A, l5 ? D : B }; }
    { float A=rlane(e0r_,3), B=rlane(e0i_,3), C=rlane(e1r_,3), D=rlane(e1i_,3);
      Eq3 = { l4 ? C : A, l4 ? D : B }; }
    { float A=rlane(e0r_,4), B=rlane(e0i_,4), C=rlane(e1r_,4), D=rlane(e1i_,4);
      Eq4 = { l3 ? C : A, l3 ? D : B }; }
    E1[0] = { rlane(e0r_,1), rlane(e0i_,1) };
    E1[1] = { rlane(e1r_,1), rlane(e1i_,1) };
    E2[0] = { rlane(e0r_,2), rlane(e0i_,2) };
    E2[1] = { rlane(e1r_,2), rlane(e1i_,2) };

    // ---- embed ----
    Cf F = cmul(cmul(Fv, Eq0), cmul(Eq3, Eq4));
    float2 a[4];
    #pragma unroll
    for (int r = 0; r < 4; ++r) {
      Cf P = cmul(E1[(r>>1)&1], E2[r&1]);
      Cf A = cmul(F, P);
      a[r].x = A.r; a[r].y = A.i;
    }

    // ---- layer 1 CRXs (local) ----
    rxmix(a[0], a[2], c1p, s1p);
    rxmix(a[1], a[3], c1p, s1p);
    rxmix(a[2], a[3], c2v, s2v);
    rxs<16>(a[1], c3v, s3v);
    rxs<16>(a[3], c3v, s3v);
    rxs<8>(a[0], c4p, s4p);
    rxs<8>(a[1], c4p, s4p);
    rxs<8>(a[2], c4p, s4p);
    rxs<8>(a[3], c4p, s4p);

    // ---- layer 2: q0..q7 local ----
    lgate<32>(a[0], q0row); lgate<32>(a[1], q0row);
    lgate<32>(a[2], q0row); lgate<32>(a[3], q0row);
    rgate(a[0], a[2], Mq1);
    rgate(a[1], a[3], Mq1);
    rgate(a[0], a[1], Mq2a);
    rgate(a[2], a[3], Mq2b);
    lgate<16>(a[0], q3rowU); lgate<16>(a[2], q3rowU);
    lgate<16>(a[1], q3rowV); lgate<16>(a[3], q3rowV);
    lgate<8>(a[0], q4row);  lgate<8>(a[1], q4row);
    lgate<8>(a[2], q4row);  lgate<8>(a[3], q4row);
    lgate<4>(a[0], q5row);  lgate<4>(a[1], q5row);
    lgate<4>(a[2], q5row);  lgate<4>(a[3], q5row);
    lgate<2>(a[0], q6row);  lgate<2>(a[1], q6row);
    lgate<2>(a[2], q6row);  lgate<2>(a[3], q6row);
    lgate<1>(a[0], q7row);  lgate<1>(a[1], q7row);
    lgate<1>(a[2], q7row);  lgate<1>(a[3], q7row);

    // ---- PRE-merge expectations (exact for q0..q7 by unitarity) ----
    float p0 = a[0].x*a[0].x + a[0].y*a[0].y;
    float p1 = a[1].x*a[1].x + a[1].y*a[1].y;
    float p2 = a[2].x*a[2].x + a[2].y*a[2].y;
    float p3 = a[3].x*a[3].x + a[3].y*a[3].y;
    float P  = p0+p1+p2+p3;
    float Z1 = (p0+p1)-(p2+p3);                // q1 (r1)
    float Z2 = (p0-p1)+(p2-p3);                // q2 (r0)
    float T0,T1,T2,T3,T4,T5;
    { float xx=sx<1>(P);  T0=(lane&1) ? xx-P : P-xx; P+=xx;
      Z1+=sx<1>(Z1); Z2+=sx<1>(Z2); }
    { float xx=sx<2>(P);  T1=(lane&2) ? xx-P : P-xx; P+=xx;
      Z1+=sx<2>(Z1); Z2+=sx<2>(Z2); T0+=sx<2>(T0); }
    { float xx=sx<4>(P);  T2=(lane&4) ? xx-P : P-xx; P+=xx;
      Z1+=sx<4>(Z1); Z2+=sx<4>(Z2); T0+=sx<4>(T0); T1+=sx<4>(T1); }
    { float xx=sx<8>(P);  T3=(lane&8) ? xx-P : P-xx; P+=xx;
      Z1+=sx<8>(Z1); Z2+=sx<8>(Z2); T0+=sx<8>(T0); T1+=sx<8>(T1); T2+=sx<8>(T2); }
    { float xx=sx<16>(P); T4=(lane&16)? xx-P : P-xx; P+=xx;
      Z1+=sx<16>(Z1); Z2+=sx<16>(Z2); T0+=sx<16>(T0); T1+=sx<16>(T1);
      T2+=sx<16>(T2); T3+=sx<16>(T3); }
    { float xx=sx<32>(P); T5=(lane&32)? xx-P : P-xx; P+=xx;
      Z1+=sx<32>(Z1); Z2+=sx<32>(Z2); T0+=sx<32>(T0); T1+=sx<32>(T1);
      T2+=sx<32>(T2); T3+=sx<32>(T3); T4+=sx<32>(T4); }
    if (lane == 0) {
      wredT[0][w]=Z1; wredT[1][w]=Z2; wredT[2][w]=T0; wredT[3][w]=T1;
      wredT[4][w]=T2; wredT[5][w]=T3; wredT[6][w]=T4; wredT[7][w]=T5;
    }
    __syncthreads();                            // ---- barrier A ----

    // hidden update (all waves, lanes 0..4): q0->T5(7) q1->Z1(0) q2->Z2(1)
    //                                        q3->T4(6) q4->T3(5)
    if (lane < 5) {
      int slot = (lane==0) ? 7 : (lane==1) ? 0 : (lane==2) ? 1 : (lane==3) ? 6 : 5;
      float4 A4 = *(const float4*)&wredT[slot][0];
      float4 B4 = *(const float4*)&wredT[slot][4];
      hreg = (A4.x+A4.y+A4.z+A4.w) + (B4.x+B4.y+B4.z+B4.w);
      if (t == TSTEPS-1 && w == 0)
        out[BATCH*TSTEPS*6 + b*5 + lane] = hreg;
    }
    // o0..o2 (this step): w0 lanes 5..7: q5->T2(4) q6->T1(3) q7->T0(2)
    if (w == 0 && lane >= 5 && lane < 8) {
      int slot = (lane==5) ? 4 : (lane==6) ? 3 : 2;
      float4 A4 = *(const float4*)&wredT[slot][0];
      float4 B4 = *(const float4*)&wredT[slot][4];
      out[(size_t)b*TSTEPS*6 + t*6 + (lane-5)] =
          (A4.x+A4.y+A4.z+A4.w) + (B4.x+B4.y+B4.z+B4.w);
    }
    // o3..o5 (PREVIOUS step, deferred): w1 lanes 0..2, signed sums of sredT
    if (w == 1 && lane < 3 && t > 0) {
      float4 A4 = *(const float4*)&sredT[0];
      float4 B4 = *(const float4*)&sredT[4];
      float z;
      if (lane == 0)       // q8: wave bit2
        z = (A4.x+A4.y+A4.z+A4.w) - (B4.x+B4.y+B4.z+B4.w);
      else if (lane == 1)  // q9: wave bit1
        z = (A4.x+A4.y) - (A4.z+A4.w) + (B4.x+B4.y) - (B4.z+B4.w);
      else                 // q10: wave bit0
        z = (A4.x-A4.y) + (A4.z-A4.w) + (B4.x-B4.y) + (B4.z-B4.w);
      out[(size_t)b*TSTEPS*6 + (t-1)*6 + 3 + lane] = z;
    }

    // ---- deferred merge (off recurrence path) ----
    xbA[(w<<6)+lane] = make_float4(a[0].x, a[0].y, a[1].x, a[1].y);
    xbB[(w<<6)+lane] = make_float4(a[2].x, a[2].y, a[3].x, a[3].y);
    __syncthreads();                            // ---- barrier B ----
    {
      float2 n[4];
      #pragma unroll
      for (int r = 0; r < 4; ++r) {
        n[r].x = dR[0]*a[r].x - dI[0]*a[r].y;
        n[r].y = dR[0]*a[r].y + dI[0]*a[r].x;
      }
      #pragma unroll
      for (int k = 1; k < 8; ++k) {
        const int j = w ^ k;
        float4 p01 = xbA[(j<<6)+lane];
        float4 p23 = xbB[(j<<6)+lane];
        n[0].x += dR[k]*p01.x - dI[k]*p01.y; n[0].y += dR[k]*p01.y + dI[k]*p01.x;
        n[1].x += dR[k]*p01.z - dI[k]*p01.w; n[1].y += dR[k]*p01.w + dI[k]*p01.z;
        n[2].x += dR[k]*p23.x - dI[k]*p23.y; n[2].y += dR[k]*p23.y + dI[k]*p23.x;
        n[3].x += dR[k]*p23.z - dI[k]*p23.w; n[3].y += dR[k]*p23.w + dI[k]*p23.z;
      }
      float S = (n[0].x*n[0].x + n[0].y*n[0].y) + (n[1].x*n[1].x + n[1].y*n[1].y)
              + (n[2].x*n[2].x + n[2].y*n[2].y) + (n[3].x*n[3].x + n[3].y*n[3].y);
      S += sx<1>(S);  S += sx<2>(S);  S += sx<4>(S);
      S += sx<8>(S);  S += sx<16>(S); S += sx<32>(S);
      if (lane == 0) sredT[w] = S;
      // consumed after NEXT barrier A (or post-loop); WAR-safe via barrier B
    }
  }

  // ---- tail: finalize t=47's o3..o5 ----
  __syncthreads();
  if (w == 1 && lane < 3) {
    float4 A4 = *(const float4*)&sredT[0];
    float4 B4 = *(const float4*)&sredT[4];
    float z;
    if (lane == 0)
      z = (A4.x+A4.y+A4.z+A4.w) - (B4.x+B4.y+B4.z+B4.w);
    else if (lane == 1)
      z = (A4.x+A4.y) - (A4.z+A4.w) + (B4.x+B4.y) - (B4.z+B4.w);
    else
      z = (A4.x-A4.y) + (A4.z-A4.w) + (B4.x-B4.y) + (B4.z-B4.w);
    out[(size_t)b*TSTEPS*6 + (TSTEPS-1)*6 + 3 + lane] = z;
  }
}

extern "C" void kernel_launch(void* const* d_in, const int* in_sizes, int n_in,
                              void* d_out, int out_size, void* d_ws, size_t ws_size,
                              hipStream_t stream) {
  const float* x      = (const float*)d_in[0];
  const float* hidden = (const float*)d_in[1];
  const float* params = (const float*)d_in[2];
  float* out          = (float*)d_out;
  qrnn_kernel<<<dim3(BATCH), dim3(BLOCK), 0, stream>>>(x, hidden, params, out);
}

// Round 6
// 241.728 us; speedup vs baseline: 1.0014x; 1.0014x over previous
//
#include <hip/hip_runtime.h>
#include <math.h>

#define TSTEPS 48
#define FEAT 60
#define BATCH 128
#define BLOCK 512
#define TWO_PI_F 6.2831853071795864769f

// BLOCK=512: 8 waves/block -> 2 waves/SIMD, 4 amps/thread.
// qubits: q0=l5 q1=r1 q2=r0 q3=l4 q4=l3 q5=l2 q6=l1 q7=l0 q8=w2 q9=w1 q10=w0
// L1 1q gates folded into embedding; L1 CRXs local. L2 q0..q7 local (CRX
// fused). L2 q8..q10 = 8x8 wave merge. SINGLE barrier per step: the merge of
// step t-1 is computed inside step t's body (independent instruction stream,
// overlaps the hreg->embed->gates serial chain); exchange planes, wredT and
// sredT are parity double-buffered so no second barrier is needed.

struct Cf { float r, i; };
__device__ __forceinline__ Cf cmul(Cf a, Cf b){ return {a.r*b.r - a.i*b.i, a.r*b.i + a.i*b.r}; }
__device__ __forceinline__ Cf cadd(Cf a, Cf b){ return {a.r+b.r, a.i+b.i}; }
__device__ __forceinline__ void mm2(const Cf A[4], const Cf B[4], Cf D[4]) {
  D[0] = cadd(cmul(A[0],B[0]), cmul(A[1],B[2]));
  D[1] = cadd(cmul(A[0],B[1]), cmul(A[1],B[3]));
  D[2] = cadd(cmul(A[2],B[0]), cmul(A[3],B[2]));
  D[3] = cadd(cmul(A[2],B[1]), cmul(A[3],B[3]));
}

struct Mat { float4 r0, r1; };

__device__ __forceinline__ float rlane(float v, int l) {
  return __int_as_float(__builtin_amdgcn_readlane(__float_as_int(v), l));
}

template<int CTRL>
__device__ __forceinline__ float dppf(float v) {
  return __int_as_float(__builtin_amdgcn_mov_dpp(__float_as_int(v), CTRL, 0xF, 0xF, true));
}

// xor-lane exchange. 1,2:quad_perm 4:reverse∘half_mirror 8:row_ror:8
// 16,32: ds_swizzle/permute via __shfl_xor
template<int M>
__device__ __forceinline__ float sx(float v) {
  if constexpr (M == 1)      return dppf<0xB1>(v);
  else if constexpr (M == 2) return dppf<0x4E>(v);
  else if constexpr (M == 4) return dppf<0x141>(dppf<0x1B>(v));
  else if constexpr (M == 8) return dppf<0x128>(v);
  else return __shfl_xor(v, M, 64);
}

__device__ __forceinline__ Cf csel(float4 v, int b) {
  return b ? Cf{v.z, v.w} : Cf{v.x, v.y};
}

__device__ __forceinline__ float4 rowsel(const float* M, int bit) {
  return bit ? make_float4(M[6],M[7],M[4],M[5])
             : make_float4(M[0],M[1],M[2],M[3]);
}

template<int MASK>
__device__ __forceinline__ void lgate(float2& a, float4 m) {
  float px = sx<MASK>(a.x), py = sx<MASK>(a.y);
  float ax = a.x, ay = a.y;
  a.x = m.x*ax - m.y*ay + m.z*px - m.w*py;
  a.y = m.x*ay + m.y*ax + m.z*py + m.w*px;
}

__device__ __forceinline__ void rgate(float2& A, float2& B, Mat M) {
  float2 A0 = A, B0 = B;
  A.x = M.r0.x*A0.x - M.r0.y*A0.y + M.r0.z*B0.x - M.r0.w*B0.y;
  A.y = M.r0.x*A0.y + M.r0.y*A0.x + M.r0.z*B0.y + M.r0.w*B0.x;
  B.x = M.r1.x*A0.x - M.r1.y*A0.y + M.r1.z*B0.x - M.r1.w*B0.y;
  B.y = M.r1.x*A0.y + M.r1.y*A0.x + M.r1.z*B0.y + M.r1.w*B0.x;
}

__device__ __forceinline__ void rxmix(float2& a0, float2& a1, float c, float s) {
  float n0x = c*a0.x + s*a1.y, n0y = c*a0.y - s*a1.x;
  float n1x = c*a1.x + s*a0.y, n1y = c*a1.y - s*a0.x;
  a0.x = n0x; a0.y = n0y; a1.x = n1x; a1.y = n1y;
}

template<int MASK>
__device__ __forceinline__ void rxs(float2& a, float c, float s) {
  float px = sx<MASK>(a.x), py = sx<MASK>(a.y);
  float ax = a.x, ay = a.y;
  a.x = c*ax + s*py;
  a.y = c*ay - s*px;
}

__global__ __launch_bounds__(BLOCK, 2)
void qrnn_kernel(const float* __restrict__ x, const float* __restrict__ hin,
                 const float* __restrict__ params, float* __restrict__ out) {
  const int b    = blockIdx.x;
  const int tid  = threadIdx.x;
  const int lane = tid & 63;
  const int w    = tid >> 6;                   // 0..7
  const int l5 = (lane>>5)&1, l4=(lane>>4)&1, l3=(lane>>3)&1,
            l2 = (lane>>2)&1, l1=(lane>>1)&1, l0=lane&1;

  __shared__ __align__(16) float matU[2][11][8];
  __shared__ __align__(16) float matVs[4][8];
  __shared__ float  xs[TSTEPS*FEAT];
  __shared__ float  pooled[TSTEPS][6];
  __shared__ float4 evis[TSTEPS][6];
  __shared__ __align__(16) float4 xbA[2][512];   // parity-buffered planes
  __shared__ __align__(16) float4 xbB[2][512];
  __shared__ __align__(16) float wredT[2][8][8]; // [parity][slot][wave]
  __shared__ __align__(16) float sredT[2][8];    // [parity][wave]

  // ---- stage x ----
  for (int j = tid; j < TSTEPS*FEAT; j += BLOCK)
    xs[j] = x[(size_t)b*TSTEPS*FEAT + j];
  // ---- fused per-(layer,qubit) U = RZ*RY*RX ----
  if (tid < 22) {
    int l = tid / 11, k = tid % 11;
    int base = 37 * l;
    int off = (k < 5) ? (base + 3*k) : (base + 19 + 3*(k-5));
    float px = params[off], py = params[off+1], pz = params[off+2];
    float cx = cosf(0.5f*px), sxn = sinf(0.5f*px);
    float cy = cosf(0.5f*py), syn = sinf(0.5f*py);
    float cz = cosf(0.5f*pz), szn = sinf(0.5f*pz);
    Cf RX[4] = {{cx,0.f},{0.f,-sxn},{0.f,-sxn},{cx,0.f}};
    Cf RY[4] = {{cy,0.f},{-syn,0.f},{syn,0.f},{cy,0.f}};
    Cf RZ[4] = {{cz,-szn},{0.f,0.f},{0.f,0.f},{cz,szn}};
    Cf M[4], U[4];
    mm2(RY, RX, M);
    mm2(RZ, M,  U);
    float* d = &matU[l][k][0];
    d[0]=U[0].r; d[1]=U[0].i; d[2]=U[1].r; d[3]=U[1].i;
    d[4]=U[2].r; d[5]=U[2].i; d[6]=U[3].r; d[7]=U[3].i;
  }
  __syncthreads();
  if (tid < 4) {                                // V[i] = RX(th_L2,i)*U2[i+1]
    float th = params[37 + 15 + tid];
    float c = cosf(0.5f*th), s = sinf(0.5f*th);
    const float* Up = &matU[1][tid+1][0];
    Cf U00{Up[0],Up[1]}, U01{Up[2],Up[3]}, U10{Up[4],Up[5]}, U11{Up[6],Up[7]};
    Cf ms{0.f, -s};
    Cf V00 = cadd(Cf{c*U00.r, c*U00.i}, cmul(ms, U10));
    Cf V01 = cadd(Cf{c*U01.r, c*U01.i}, cmul(ms, U11));
    Cf V10 = cadd(cmul(ms, U00), Cf{c*U10.r, c*U10.i});
    Cf V11 = cadd(cmul(ms, U01), Cf{c*U11.r, c*U11.i});
    float* d = &matVs[tid][0];
    d[0]=V00.r; d[1]=V00.i; d[2]=V01.r; d[3]=V01.i;
    d[4]=V10.r; d[5]=V10.i; d[6]=V11.r; d[7]=V11.i;
  }
  for (int j = tid; j < TSTEPS*6; j += BLOCK) {
    int t = j / 6, k = j % 6;
    const float* xp = &xs[t*FEAT + k*10];
    float s = 0.f;
    #pragma unroll
    for (int f = 0; f < 10; ++f) s += xp[f];
    pooled[t][k] = s * 0.1f;
  }
  __syncthreads();
  for (int j = tid; j < TSTEPS*6; j += BLOCK) {
    int t = j / 6, k = j % 6;
    float mn = pooled[t][0], mx = pooled[t][0];
    #pragma unroll
    for (int v = 1; v < 6; ++v) { mn = fminf(mn, pooled[t][v]); mx = fmaxf(mx, pooled[t][v]); }
    float ang = TWO_PI_F * (pooled[t][k] - mn) / (mx - mn + 1e-8f);
    float c = __cosf(0.5f*ang), s = __sinf(0.5f*ang);
    const float* U = &matU[0][5+k][0];
    evis[t][k] = make_float4(U[0]*c + U[3]*s, U[1]*c - U[2]*s,
                             U[4]*c + U[7]*s, U[5]*c - U[6]*s);
  }

  // ---- per-thread loop-invariant gate data ----
  Mat Mq1;
  { const float* p = l5 ? &matVs[0][0] : &matU[1][1][0];
    Mq1.r0 = *(const float4*)p; Mq1.r1 = *(const float4*)(p+4); }
  Mat Mq2a, Mq2b;
  Mq2a.r0 = *(const float4*)&matU[1][2][0]; Mq2a.r1 = *(const float4*)&matU[1][2][4];
  Mq2b.r0 = *(const float4*)&matVs[1][0];   Mq2b.r1 = *(const float4*)&matVs[1][4];
  float4 q0row  = rowsel(&matU[1][0][0], l5);
  float4 q3rowU = rowsel(&matU[1][3][0], l4);
  float4 q3rowV = rowsel(&matVs[2][0],   l4);
  float4 q4row  = rowsel(l4 ? &matVs[3][0] : &matU[1][4][0], l3);
  float4 q5row  = rowsel(&matU[1][5][0], l2);
  float4 q6row  = rowsel(&matU[1][6][0], l1);
  float4 q7row  = rowsel(&matU[1][7][0], l0);
  float c1p, s1p, c2v, s2v, c3v, s3v, c4p, s4p;
  { float th = params[15]; float c = cosf(0.5f*th), s = sinf(0.5f*th);
    c1p = l5 ? c : 1.f; s1p = l5 ? s : 0.f; }
  { float th = params[16]; c2v = cosf(0.5f*th); s2v = sinf(0.5f*th); }
  { float th = params[17]; c3v = cosf(0.5f*th); s3v = sinf(0.5f*th); }
  { float th = params[18]; float c = cosf(0.5f*th), s = sinf(0.5f*th);
    c4p = l4 ? c : 1.f; s4p = l4 ? s : 0.f; }
  // merge coefficients (8x8 tensor row, XOR-indexed)
  float dR[8], dI[8];
  { const int i2 = (w>>2)&1, i1 = (w>>1)&1, i0 = w&1;
    const float* u8  = &matU[1][8][0];
    const float* u9  = &matU[1][9][0];
    const float* u10 = &matU[1][10][0];
    #pragma unroll
    for (int k = 0; k < 8; ++k) {
      int j = w ^ k;
      int j2 = (j>>2)&1, j1 = (j>>1)&1, j0 = j&1;
      Cf a8 {u8 [(i2*2+j2)*2], u8 [(i2*2+j2)*2+1]};
      Cf a9 {u9 [(i1*2+j1)*2], u9 [(i1*2+j1)*2+1]};
      Cf a10{u10[(i0*2+j0)*2], u10[(i0*2+j0)*2+1]};
      Cf c = cmul(cmul(a8, a9), a10);
      dR[k] = c.r; dI[k] = c.i;
    }
  }
  const int lq = (lane < 5) ? lane : 0;
  float4 mH0 = *(const float4*)&matU[0][lq][0];
  float4 mH1 = *(const float4*)&matU[0][lq][4];
  float hreg = (lane < 5) ? hin[b*5 + lane] : 0.f;
  __syncthreads();

  #pragma unroll 1
  for (int t = 0; t < TSTEPS; ++t) {
    const int cb = t & 1;          // current parity
    const int pb = cb ^ 1;         // previous parity

    // ==== stream B: merge of step t-1 (independent of hreg chain) ====
    if (t > 0) {
      float2 n0{0,0}, n1{0,0}, n2{0,0}, n3{0,0};
      #pragma unroll
      for (int k = 0; k < 8; ++k) {
        const int j = w ^ k;
        float4 p01 = xbA[pb][(j<<6)+lane];
        float4 p23 = xbB[pb][(j<<6)+lane];
        n0.x += dR[k]*p01.x - dI[k]*p01.y; n0.y += dR[k]*p01.y + dI[k]*p01.x;
        n1.x += dR[k]*p01.z - dI[k]*p01.w; n1.y += dR[k]*p01.w + dI[k]*p01.z;
        n2.x += dR[k]*p23.x - dI[k]*p23.y; n2.y += dR[k]*p23.y + dI[k]*p23.x;
        n3.x += dR[k]*p23.z - dI[k]*p23.w; n3.y += dR[k]*p23.w + dI[k]*p23.z;
      }
      float S = (n0.x*n0.x + n0.y*n0.y) + (n1.x*n1.x + n1.y*n1.y)
              + (n2.x*n2.x + n2.y*n2.y) + (n3.x*n3.x + n3.y*n3.y);
      S += sx<1>(S);  S += sx<2>(S);  S += sx<4>(S);
      S += sx<8>(S);  S += sx<16>(S); S += sx<32>(S);
      if (lane == 0) sredT[pb][w] = S;
    }

    // ==== stream A: step t embed -> gates (hreg-dependent chain) ====
    float4 v5 = evis[t][0], v6 = evis[t][1], v7 = evis[t][2],
           v8 = evis[t][3], v9 = evis[t][4], v10 = evis[t][5];
    Cf Fv = csel(v8, (w>>2)&1);
    Fv = cmul(Fv, csel(v9, (w>>1)&1));
    Fv = cmul(Fv, csel(v10, w&1));
    Fv = cmul(Fv, csel(v5, l2));
    Fv = cmul(Fv, csel(v6, l1));
    Fv = cmul(Fv, csel(v7, l0));

    float chh = __cosf(0.5f*hreg), shh = __sinf(0.5f*hreg);
    float e0r_ = mH0.x*chh + mH0.w*shh;
    float e0i_ = mH0.y*chh - mH0.z*shh;
    float e1r_ = mH1.x*chh + mH1.w*shh;
    float e1i_ = mH1.y*chh - mH1.z*shh;
    Cf Eq0, Eq3, Eq4, E1[2], E2[2];
    { float A=rlane(e0r_,0), B=rlane(e0i_,0), C=rlane(e1r_,0), D=rlane(e1i_,0);
      Eq0 = { l5 ? C : A, l5 ? D : B }; }
    { float A=rlane(e0r_,3), B=rlane(e0i_,3), C=rlane(e1r_,3), D=rlane(e1i_,3);
      Eq3 = { l4 ? C : A, l4 ? D : B }; }
    { float A=rlane(e0r_,4), B=rlane(e0i_,4), C=rlane(e1r_,4), D=rlane(e1i_,4);
      Eq4 = { l3 ? C : A, l3 ? D : B }; }
    E1[0] = { rlane(e0r_,1), rlane(e0i_,1) };
    E1[1] = { rlane(e1r_,1), rlane(e1i_,1) };
    E2[0] = { rlane(e0r_,2), rlane(e0i_,2) };
    E2[1] = { rlane(e1r_,2), rlane(e1i_,2) };

    Cf F = cmul(cmul(Fv, Eq0), cmul(Eq3, Eq4));
    float2 a[4];
    #pragma unroll
    for (int r = 0; r < 4; ++r) {
      Cf P = cmul(E1[(r>>1)&1], E2[r&1]);
      Cf A = cmul(F, P);
      a[r].x = A.r; a[r].y = A.i;
    }

    // layer 1 CRXs (local)
    rxmix(a[0], a[2], c1p, s1p);
    rxmix(a[1], a[3], c1p, s1p);
    rxmix(a[2], a[3], c2v, s2v);
    rxs<16>(a[1], c3v, s3v);
    rxs<16>(a[3], c3v, s3v);
    rxs<8>(a[0], c4p, s4p);
    rxs<8>(a[1], c4p, s4p);
    rxs<8>(a[2], c4p, s4p);
    rxs<8>(a[3], c4p, s4p);

    // layer 2: q0..q7 local
    lgate<32>(a[0], q0row); lgate<32>(a[1], q0row);
    lgate<32>(a[2], q0row); lgate<32>(a[3], q0row);
    rgate(a[0], a[2], Mq1);
    rgate(a[1], a[3], Mq1);
    rgate(a[0], a[1], Mq2a);
    rgate(a[2], a[3], Mq2b);
    lgate<16>(a[0], q3rowU); lgate<16>(a[2], q3rowU);
    lgate<16>(a[1], q3rowV); lgate<16>(a[3], q3rowV);
    lgate<8>(a[0], q4row);  lgate<8>(a[1], q4row);
    lgate<8>(a[2], q4row);  lgate<8>(a[3], q4row);
    lgate<4>(a[0], q5row);  lgate<4>(a[1], q5row);
    lgate<4>(a[2], q5row);  lgate<4>(a[3], q5row);
    lgate<2>(a[0], q6row);  lgate<2>(a[1], q6row);
    lgate<2>(a[2], q6row);  lgate<2>(a[3], q6row);
    lgate<1>(a[0], q7row);  lgate<1>(a[1], q7row);
    lgate<1>(a[2], q7row);  lgate<1>(a[3], q7row);

    // pre-merge expectations (exact for q0..q7 by unitarity of the merge)
    float p0 = a[0].x*a[0].x + a[0].y*a[0].y;
    float p1 = a[1].x*a[1].x + a[1].y*a[1].y;
    float p2 = a[2].x*a[2].x + a[2].y*a[2].y;
    float p3 = a[3].x*a[3].x + a[3].y*a[3].y;
    float P  = p0+p1+p2+p3;
    float Z1 = (p0+p1)-(p2+p3);                // q1 (r1)
    float Z2 = (p0-p1)+(p2-p3);                // q2 (r0)
    float T0,T1,T2,T3,T4,T5;
    { float xx=sx<1>(P);  T0=(lane&1) ? xx-P : P-xx; P+=xx;
      Z1+=sx<1>(Z1); Z2+=sx<1>(Z2); }
    { float xx=sx<2>(P);  T1=(lane&2) ? xx-P : P-xx; P+=xx;
      Z1+=sx<2>(Z1); Z2+=sx<2>(Z2); T0+=sx<2>(T0); }
    { float xx=sx<4>(P);  T2=(lane&4) ? xx-P : P-xx; P+=xx;
      Z1+=sx<4>(Z1); Z2+=sx<4>(Z2); T0+=sx<4>(T0); T1+=sx<4>(T1); }
    { float xx=sx<8>(P);  T3=(lane&8) ? xx-P : P-xx; P+=xx;
      Z1+=sx<8>(Z1); Z2+=sx<8>(Z2); T0+=sx<8>(T0); T1+=sx<8>(T1); T2+=sx<8>(T2); }
    { float xx=sx<16>(P); T4=(lane&16)? xx-P : P-xx; P+=xx;
      Z1+=sx<16>(Z1); Z2+=sx<16>(Z2); T0+=sx<16>(T0); T1+=sx<16>(T1);
      T2+=sx<16>(T2); T3+=sx<16>(T3); }
    { float xx=sx<32>(P); T5=(lane&32)? xx-P : P-xx; P+=xx;
      Z1+=sx<32>(Z1); Z2+=sx<32>(Z2); T0+=sx<32>(T0); T1+=sx<32>(T1);
      T2+=sx<32>(T2); T3+=sx<32>(T3); T4+=sx<32>(T4); }
    if (lane == 0) {
      wredT[cb][0][w]=Z1; wredT[cb][1][w]=Z2; wredT[cb][2][w]=T0; wredT[cb][3][w]=T1;
      wredT[cb][4][w]=T2; wredT[cb][5][w]=T3; wredT[cb][6][w]=T4; wredT[cb][7][w]=T5;
    }
    // publish pre-merge amps for step t's merge (consumed next iteration)
    xbA[cb][(w<<6)+lane] = make_float4(a[0].x, a[0].y, a[1].x, a[1].y);
    xbB[cb][(w<<6)+lane] = make_float4(a[2].x, a[2].y, a[3].x, a[3].y);

    __syncthreads();                            // ---- the ONE barrier ----

    // hidden update: q0->T5(7) q1->Z1(0) q2->Z2(1) q3->T4(6) q4->T3(5)
    if (lane < 5) {
      int slot = (lane==0) ? 7 : (lane==1) ? 0 : (lane==2) ? 1 : (lane==3) ? 6 : 5;
      float4 A4 = *(const float4*)&wredT[cb][slot][0];
      float4 B4 = *(const float4*)&wredT[cb][slot][4];
      hreg = (A4.x+A4.y+A4.z+A4.w) + (B4.x+B4.y+B4.z+B4.w);
      if (t == TSTEPS-1 && w == 0)
        out[BATCH*TSTEPS*6 + b*5 + lane] = hreg;
    }
    // o0..o2 (step t): w0 lanes 5..7: q5->T2(4) q6->T1(3) q7->T0(2)
    if (w == 0 && lane >= 5 && lane < 8) {
      int slot = (lane==5) ? 4 : (lane==6) ? 3 : 2;
      float4 A4 = *(const float4*)&wredT[cb][slot][0];
      float4 B4 = *(const float4*)&wredT[cb][slot][4];
      out[(size_t)b*TSTEPS*6 + t*6 + (lane-5)] =
          (A4.x+A4.y+A4.z+A4.w) + (B4.x+B4.y+B4.z+B4.w);
    }
    // o3..o5 (step t-1): w1 lanes 0..2, signed sums of sredT[pb]
    if (w == 1 && lane < 3 && t > 0) {
      float4 A4 = *(const float4*)&sredT[pb][0];
      float4 B4 = *(const float4*)&sredT[pb][4];
      float z;
      if (lane == 0)       // q8: wave bit2
        z = (A4.x+A4.y+A4.z+A4.w) - (B4.x+B4.y+B4.z+B4.w);
      else if (lane == 1)  // q9: wave bit1
        z = (A4.x+A4.y) - (A4.z+A4.w) + (B4.x+B4.y) - (B4.z+B4.w);
      else                 // q10: wave bit0
        z = (A4.x-A4.y) + (A4.z-A4.w) + (B4.x-B4.y) + (B4.z-B4.w);
      out[(size_t)b*TSTEPS*6 + (t-1)*6 + 3 + lane] = z;
    }
  }

  // ---- tail: merge of t=47 and its o3..o5 ----
  {
    const int pb = (TSTEPS-1) & 1;   // = 1
    float2 n0{0,0}, n1{0,0}, n2{0,0}, n3{0,0};
    #pragma unroll
    for (int k = 0; k < 8; ++k) {
      const int j = w ^ k;
      float4 p01 = xbA[pb][(j<<6)+lane];
      float4 p23 = xbB[pb][(j<<6)+lane];
      n0.x += dR[k]*p01.x - dI[k]*p01.y; n0.y += dR[k]*p01.y + dI[k]*p01.x;
      n1.x += dR[k]*p01.z - dI[k]*p01.w; n1.y += dR[k]*p01.w + dI[k]*p01.z;
      n2.x += dR[k]*p23.x - dI[k]*p23.y; n2.y += dR[k]*p23.y + dI[k]*p23.x;
      n3.x += dR[k]*p23.z - dI[k]*p23.w; n3.y += dR[k]*p23.w + dI[k]*p23.z;
    }
    float S = (n0.x*n0.x + n0.y*n0.y) + (n1.x*n1.x + n1.y*n1.y)
            + (n2.x*n2.x + n2.y*n2.y) + (n3.x*n3.x + n3.y*n3.y);
    S += sx<1>(S);  S += sx<2>(S);  S += sx<4>(S);
    S += sx<8>(S);  S += sx<16>(S); S += sx<32>(S);
    if (lane == 0) sredT[pb][w] = S;
    __syncthreads();
    if (w == 1 && lane < 3) {
      float4 A4 = *(const float4*)&sredT[pb][0];
      float4 B4 = *(const float4*)&sredT[pb][4];
      float z;
      if (lane == 0)
        z = (A4.x+A4.y+A4.z+A4.w) - (B4.x+B4.y+B4.z+B4.w);
      else if (lane == 1)
        z = (A4.x+A4.y) - (A4.z+A4.w) + (B4.x+B4.y) - (B4.z+B4.w);
      else
        z = (A4.x-A4.y) + (A4.z-A4.w) + (B4.x-B4.y) + (B4.z-B4.w);
      out[(size_t)b*TSTEPS*6 + (TSTEPS-1)*6 + 3 + lane] = z;
    }
  }
}

extern "C" void kernel_launch(void* const* d_in, const int* in_sizes, int n_in,
                              void* d_out, int out_size, void* d_ws, size_t ws_size,
                              hipStream_t stream) {
  const float* x      = (const float*)d_in[0];
  const float* hidden = (const float*)d_in[1];
  const float* params = (const float*)d_in[2];
  float* out          = (float*)d_out;
  qrnn_kernel<<<dim3(BATCH), dim3(BLOCK), 0, stream>>>(x, hidden, params, out);
}